// Round 1
// 259.506 us; speedup vs baseline: 1.0605x; 1.0605x over previous
//
#include <hip/hip_runtime.h>
#include <hip/hip_bf16.h>
#include <math.h>

#define B_SZ   4096
#define H_LEN  256
#define D_DIM  128
#define K_HEADS 4
#define H1_DIM 512
#define H2_DIM 256

#define CH     64     // history rows per chunk
#define NCH    4      // chunks
#define TPAD   132    // tile row stride (floats): 16B-aligned

typedef __attribute__((ext_vector_type(8))) short bf16x8;   // 8 bf16 (4 VGPRs)
typedef __attribute__((ext_vector_type(4))) float f32x4;

// ---------------------------------------------------------------------------
// Kernel 1: single-pass multi-interest extraction with register prefetch of
// the NEXT chunk's gather rows (hides random-gather latency under the
// score/pool compute of the current chunk). fp32 everywhere upstream of the
// argmax so interest selection is bit-stable vs reference.
// ---------------------------------------------------------------------------
__global__ __launch_bounds__(256, 4) void interest_kernel(
    const int*   __restrict__ cand_ids,   // (B,)
    const int*   __restrict__ hist,       // (B, H)
    const float* __restrict__ table,      // (NUM_ITEMS, D)
    const float* __restrict__ Wp,         // (D, K) row-major
    __hip_bfloat16* __restrict__ Xbf)     // (B, 2D) bf16: [selected | cand]
{
    __shared__ float tile[CH * TPAD];     // 33792 B; tail-reused for partB/ivbuf
    __shared__ float wpt[K_HEADS * D_DIM];// Wp^T [k][d]           2 KB
    __shared__ float exps4[CH * 4];       // exp(score) [h][k]     1 KB
    __shared__ float candv[D_DIM];        //                       512 B
    __shared__ int   rowids[H_LEN];       //                       1 KB
    __shared__ float lsumW[16];           // per-wave denom partials [w][k]
    __shared__ float simred[4][K_HEADS];
    __shared__ int   bestk;

    const int b    = blockIdx.x;
    const int t    = threadIdx.x;
    const int lane = t & 63, w = t >> 6;
    const int r    = t >> 2, q = t & 3;      // gather: 4 threads per row
    const int d    = t & 127, half = t >> 7; // pooling: 2 threads per d

    if (t < D_DIM) {
        float4 w4 = ((const float4*)Wp)[t];   // Wp[d=t][0..3]
        wpt[0 * D_DIM + t] = w4.x;
        wpt[1 * D_DIM + t] = w4.y;
        wpt[2 * D_DIM + t] = w4.z;
        wpt[3 * D_DIM + t] = w4.w;
    }
    const int cand = cand_ids[b];
    if (t >= 128 && t < 160) {
        int c = t - 128;
        ((float4*)candv)[c] = ((const float4*)(table + (long long)cand * D_DIM))[c];
    }
    rowids[t] = hist[(long long)b * H_LEN + t];

    __syncthreads();   // staging (rowids/wpt/candv) visible

    float a0 = 0.f, a1 = 0.f, a2 = 0.f, a3 = 0.f;  // pooling acc for (d,half)
    float l0 = 0.f, l1 = 0.f, l2 = 0.f, l3 = 0.f;  // wave-local denom partials

    // --- prefetch chunk 0 into registers ---
    float4 v0, v1, v2, v3, v4, v5, v6, v7;
    {
        const int row = rowids[r];
        const float* rp = table + (long long)row * D_DIM + (q << 2);
        v0 = *(const float4*)(rp + 0 * 16);
        v1 = *(const float4*)(rp + 1 * 16);
        v2 = *(const float4*)(rp + 2 * 16);
        v3 = *(const float4*)(rp + 3 * 16);
        v4 = *(const float4*)(rp + 4 * 16);
        v5 = *(const float4*)(rp + 5 * 16);
        v6 = *(const float4*)(rp + 6 * 16);
        v7 = *(const float4*)(rp + 7 * 16);
    }

    #pragma unroll
    for (int c = 0; c < NCH; ++c) {
        // --- issue next chunk's gather loads (overlaps with all work below) ---
        float4 u0, u1, u2, u3, u4, u5, u6, u7;
        if (c + 1 < NCH) {
            const int row = rowids[((c + 1) << 6) + r];
            const float* rp = table + (long long)row * D_DIM + (q << 2);
            u0 = *(const float4*)(rp + 0 * 16);
            u1 = *(const float4*)(rp + 1 * 16);
            u2 = *(const float4*)(rp + 2 * 16);
            u3 = *(const float4*)(rp + 3 * 16);
            u4 = *(const float4*)(rp + 4 * 16);
            u5 = *(const float4*)(rp + 5 * 16);
            u6 = *(const float4*)(rp + 6 * 16);
            u7 = *(const float4*)(rp + 7 * 16);
        }

        // --- scores + tile writes from current chunk's registers ---
        // (tile is free: trailing barrier of previous iteration, or first use)
        float s0 = 0.f, s1 = 0.f, s2 = 0.f, s3 = 0.f;
        float4 va;
        #define DO_J(J, VV)                                                     \
        {   va = VV;                                                            \
            const int cb = (q << 2) + (J << 4);                                 \
            float4 w0 = *(const float4*)(wpt + 0 * D_DIM + cb);                 \
            float4 w1 = *(const float4*)(wpt + 1 * D_DIM + cb);                 \
            float4 w2 = *(const float4*)(wpt + 2 * D_DIM + cb);                 \
            float4 w3 = *(const float4*)(wpt + 3 * D_DIM + cb);                 \
            s0 += va.x * w0.x + va.y * w0.y + va.z * w0.z + va.w * w0.w;        \
            s1 += va.x * w1.x + va.y * w1.y + va.z * w1.z + va.w * w1.w;        \
            s2 += va.x * w2.x + va.y * w2.y + va.z * w2.z + va.w * w2.w;        \
            s3 += va.x * w3.x + va.y * w3.y + va.z * w3.z + va.w * w3.w;        \
            *(float4*)(tile + (t >> 2) * TPAD + cb) = va;                       \
        }
        DO_J(0, v0) DO_J(1, v1) DO_J(2, v2) DO_J(3, v3)
        DO_J(4, v4) DO_J(5, v5) DO_J(6, v6) DO_J(7, v7)
        #undef DO_J

        // combine the 4 q-lanes of each row
        s0 += __shfl_xor(s0, 1); s0 += __shfl_xor(s0, 2);
        s1 += __shfl_xor(s1, 1); s1 += __shfl_xor(s1, 2);
        s2 += __shfl_xor(s2, 1); s2 += __shfl_xor(s2, 2);
        s3 += __shfl_xor(s3, 1); s3 += __shfl_xor(s3, 2);

        float e0 = expf(s0), e1 = expf(s1), e2 = expf(s2), e3 = expf(s3);
        if (q == 0) ((float4*)exps4)[r] = make_float4(e0, e1, e2, e3);

        // wave-sum over this wave's 16 rows
        float t0 = e0, t1 = e1, t2 = e2, t3 = e3;
        #pragma unroll
        for (int off = 4; off <= 32; off <<= 1) {
            t0 += __shfl_xor(t0, off);
            t1 += __shfl_xor(t1, off);
            t2 += __shfl_xor(t2, off);
            t3 += __shfl_xor(t3, off);
        }
        l0 += t0; l1 += t1; l2 += t2; l3 += t3;

        __syncthreads();   // tile + exps4 visible

        // --- pooling: acc[k][d] += sum over my 32 chunk rows ---
        #pragma unroll 8
        for (int i = 0; i < 32; ++i) {
            int hl = (half << 5) + i;
            float4 e4 = ((const float4*)exps4)[hl];   // broadcast
            float  vv = tile[hl * TPAD + d];
            a0 += e4.x * vv; a1 += e4.y * vv; a2 += e4.z * vv; a3 += e4.w * vv;
        }

        __syncthreads();   // tile/exps4 free for next chunk's writes

        v0 = u0; v1 = u1; v2 = u2; v3 = u3;
        v4 = u4; v5 = u5; v6 = u6; v7 = u7;
    }

    // tile reads done (trailing barrier) -> reuse tile memory
    float* partBp = tile;         // 512 floats
    float* ivbufp = tile + 512;   // 512 floats

    if (half == 1) ((float4*)partBp)[d] = make_float4(a0, a1, a2, a3);
    if (lane == 0) ((float4*)lsumW)[w]  = make_float4(l0, l1, l2, l3);
    __syncthreads();

    float s0 = 0.f, s1 = 0.f, s2 = 0.f, s3 = 0.f;
    if (half == 0) {
        float4 pb = ((const float4*)partBp)[d];
        float4 L0 = ((const float4*)lsumW)[0];
        float4 L1 = ((const float4*)lsumW)[1];
        float4 L2 = ((const float4*)lsumW)[2];
        float4 L3 = ((const float4*)lsumW)[3];
        float i0 = 1.f / (L0.x + L1.x + L2.x + L3.x);
        float i1 = 1.f / (L0.y + L1.y + L2.y + L3.y);
        float i2 = 1.f / (L0.z + L1.z + L2.z + L3.z);
        float i3 = 1.f / (L0.w + L1.w + L2.w + L3.w);
        a0 = (a0 + pb.x) * i0;
        a1 = (a1 + pb.y) * i1;
        a2 = (a2 + pb.z) * i2;
        a3 = (a3 + pb.w) * i3;
        ((float4*)ivbufp)[d] = make_float4(a0, a1, a2, a3);
        float cd = candv[d];
        s0 = a0 * cd; s1 = a1 * cd; s2 = a2 * cd; s3 = a3 * cd;
    }
    #pragma unroll
    for (int off = 32; off >= 1; off >>= 1) {
        s0 += __shfl_xor(s0, off);
        s1 += __shfl_xor(s1, off);
        s2 += __shfl_xor(s2, off);
        s3 += __shfl_xor(s3, off);
    }
    if (lane == 0) {
        simred[w][0] = s0; simred[w][1] = s1;
        simred[w][2] = s2; simred[w][3] = s3;
    }
    __syncthreads();

    if (t == 0) {
        float sim[4];
        #pragma unroll
        for (int k = 0; k < 4; ++k)
            sim[k] = simred[0][k] + simred[1][k] + simred[2][k] + simred[3][k];
        int best = 0;
        #pragma unroll
        for (int k = 1; k < 4; ++k) if (sim[k] > sim[best]) best = k;  // first-max
        bestk = best;
    }
    __syncthreads();

    __hip_bfloat16* xrow = Xbf + (long long)b * (2 * D_DIM);
    if (t < 128) xrow[t] = __float2bfloat16(ivbufp[t * 4 + bestk]);
    else         xrow[t] = __float2bfloat16(candv[t - 128]);
}

// ---------------------------------------------------------------------------
// Coalesced weight transpose+convert via 32x32 LDS tiles.
// W1 (256x512) -> W1t bf16 (512x256); W2 (512x256) -> W2t bf16 (256x512).
// 256 blocks: first 128 for W1 tiles, next 128 for W2 tiles.
// ---------------------------------------------------------------------------
__global__ __launch_bounds__(256) void convert_weights(
    const float* __restrict__ W1, const float* __restrict__ W2,
    __hip_bfloat16* __restrict__ W1t, __hip_bfloat16* __restrict__ W2t)
{
    __shared__ float tl[32][33];
    int bid = blockIdx.x;
    const float* W; __hip_bfloat16* Wt; int K, N;    // W is (K,N); Wt is (N,K)
    if (bid < 128) { W = W1; Wt = W1t; K = 2 * D_DIM; N = H1_DIM; }
    else           { W = W2; Wt = W2t; K = H1_DIM;    N = H2_DIM; bid -= 128; }
    const int ntn = N >> 5;
    const int k0 = (bid / ntn) << 5, n0 = (bid % ntn) << 5;
    const int tx = threadIdx.x & 31, ty = threadIdx.x >> 5;
    #pragma unroll
    for (int j = 0; j < 4; ++j)
        tl[ty + 8 * j][tx] = W[(long long)(k0 + ty + 8 * j) * N + n0 + tx];
    __syncthreads();
    #pragma unroll
    for (int j = 0; j < 4; ++j)
        Wt[(long long)(n0 + ty + 8 * j) * K + k0 + tx] =
            __float2bfloat16(tl[tx][ty + 8 * j]);
}

// ---------------------------------------------------------------------------
// Fused MLP tail: out = sigmoid(relu(relu(X@W1+b1)@W2+b2)@W3+b3).
// One block = 16 rows of X; h1 (bf16) and h2 (fp32) live entirely in LDS —
// no Hc1/Hc2 global round-trip, no separate head kernel.
// MFMA fragment convention identical to the previously-verified mfma_mlp:
// A[lane&15][quad*8+j], Bt[n=lane&15][quad*8+j], C col=lane&15 row=quad*4+i.
// ---------------------------------------------------------------------------
__global__ __launch_bounds__(512) void mlp_fused(
    const __hip_bfloat16* __restrict__ X,    // (B, 256)
    const __hip_bfloat16* __restrict__ W1t,  // (512, 256)
    const float* __restrict__ b1,
    const __hip_bfloat16* __restrict__ W2t,  // (256, 512)
    const float* __restrict__ b2,
    const float* __restrict__ W3,            // (256,)
    const float* __restrict__ b3,
    float*       __restrict__ out)           // (B,)
{
    __shared__ __hip_bfloat16 h1[16][H1_DIM + 8];  // pad 8 bf16: bank spread, 16B align
    __shared__ float          h2[16][H2_DIM + 4];

    const int t    = threadIdx.x;
    const int wave = t >> 6, lane = t & 63;
    const int lm   = lane & 15, quad = lane >> 4;
    const int m0   = blockIdx.x * 16;

    // ---- stage 1: h1 = relu(X @ W1 + b1); 32 N-tiles / 8 waves ----
    const __hip_bfloat16* Ap = X + (long long)(m0 + lm) * (2 * D_DIM) + quad * 8;
    bf16x8 af[8];
    #pragma unroll
    for (int it = 0; it < 8; ++it) af[it] = *(const bf16x8*)(Ap + it * 32);

    #pragma unroll
    for (int tn = 0; tn < 4; ++tn) {
        const int n0 = (wave * 4 + tn) * 16;
        const __hip_bfloat16* Bp = W1t + (long long)(n0 + lm) * (2 * D_DIM) + quad * 8;
        f32x4 acc = {0.f, 0.f, 0.f, 0.f};
        #pragma unroll
        for (int it = 0; it < 8; ++it) {
            bf16x8 bfr = *(const bf16x8*)(Bp + it * 32);
            acc = __builtin_amdgcn_mfma_f32_16x16x32_bf16(af[it], bfr, acc, 0, 0, 0);
        }
        const float bv = b1[n0 + lm];
        #pragma unroll
        for (int i = 0; i < 4; ++i)
            h1[quad * 4 + i][n0 + lm] = __float2bfloat16(fmaxf(acc[i] + bv, 0.f));
    }
    __syncthreads();

    // ---- stage 2: h2 = relu(h1 @ W2 + b2); 16 N-tiles / 8 waves ----
    bf16x8 a2[16];
    #pragma unroll
    for (int it = 0; it < 16; ++it)
        a2[it] = *(const bf16x8*)(&h1[lm][quad * 8 + it * 32]);

    #pragma unroll
    for (int tn = 0; tn < 2; ++tn) {
        const int n0 = (wave * 2 + tn) * 16;
        const __hip_bfloat16* Bp = W2t + (long long)(n0 + lm) * H1_DIM + quad * 8;
        f32x4 acc = {0.f, 0.f, 0.f, 0.f};
        #pragma unroll
        for (int it = 0; it < 16; ++it) {
            bf16x8 bfr = *(const bf16x8*)(Bp + it * 32);
            acc = __builtin_amdgcn_mfma_f32_16x16x32_bf16(a2[it], bfr, acc, 0, 0, 0);
        }
        const float bv = b2[n0 + lm];
        #pragma unroll
        for (int i = 0; i < 4; ++i)
            h2[quad * 4 + i][n0 + lm] = fmaxf(acc[i] + bv, 0.f);
    }
    __syncthreads();

    // ---- head: 32 threads per row, 8 cols each ----
    {
        const int row = t >> 5, c = (t & 31) * 8;
        float s = 0.f;
        #pragma unroll
        for (int j = 0; j < 8; ++j) s += h2[row][c + j] * W3[c + j];
        #pragma unroll
        for (int off = 1; off <= 16; off <<= 1) s += __shfl_xor(s, off);
        if ((lane & 31) == 0)
            out[m0 + row] = 1.f / (1.f + expf(-(s + b3[0])));
    }
}

// ---------------------------------------------------------------------------
extern "C" void kernel_launch(void* const* d_in, const int* in_sizes, int n_in,
                              void* d_out, int out_size, void* d_ws, size_t ws_size,
                              hipStream_t stream) {
    const int*   cand  = (const int*)  d_in[1];
    const int*   hist  = (const int*)  d_in[2];
    const float* table = (const float*)d_in[3];
    const float* Wp    = (const float*)d_in[4];
    const float* W1    = (const float*)d_in[5];
    const float* b1    = (const float*)d_in[6];
    const float* W2    = (const float*)d_in[7];
    const float* b2    = (const float*)d_in[8];
    const float* W3    = (const float*)d_in[9];
    const float* b3    = (const float*)d_in[10];
    float* out = (float*)d_out;

    // ws layout (16B-aligned regions)
    char* p = (char*)d_ws;
    __hip_bfloat16* Xbf = (__hip_bfloat16*)p;  p += (size_t)B_SZ * 2 * D_DIM * 2;   // 2 MB
    __hip_bfloat16* W1t = (__hip_bfloat16*)p;  p += (size_t)H1_DIM * 2 * D_DIM * 2; // 512 KB
    __hip_bfloat16* W2t = (__hip_bfloat16*)p;                                        // 512 KB

    convert_weights<<<256, 256, 0, stream>>>(W1, W2, W1t, W2t);
    interest_kernel<<<B_SZ, 256, 0, stream>>>(cand, hist, table, Wp, Xbf);
    mlp_fused<<<B_SZ / 16, 512, 0, stream>>>(Xbf, W1t, b1, W2t, b2, W3, b3, out);
}